// Round 15
// baseline (669.161 us; speedup 1.0000x reference)
//
#include <hip/hip_runtime.h>

typedef __attribute__((ext_vector_type(8))) short short8;
typedef __attribute__((ext_vector_type(4))) float f32x4;

#define NPTS 131072
#define NOFF 125
#define KTILE 6144                 // 12 KB/offset: 12 blocks of 512 ush
#define KERN_USH (NOFF * KTILE)

__device__ int g_isf32[4];                                     // per-input f32 flag
__device__ __align__(16) unsigned short g_x[NPTS * 128 + 128]; // x, planar layout, bf16
__device__ __align__(16) unsigned short g_kern[KERN_USH + 128];
__device__ __align__(16) float g_y[NOFF][4];                   // Y1 per offset

__device__ __forceinline__ float bf2f(unsigned short u) {
  unsigned int v = ((unsigned int)u) << 16;
  return __builtin_bit_cast(float, v);
}
__device__ __forceinline__ unsigned short f2bf(float f) {
  unsigned int x = __builtin_bit_cast(unsigned int, f);
  x += 0x7fffu + ((x >> 16) & 1u);
  return (unsigned short)(x >> 16);
}
__device__ __forceinline__ float rdf(const void* p, int i, int isf32) {
  return isf32 ? ((const float*)p)[i] : bf2f(((const unsigned short*)p)[i]);
}

// direct global->LDS, 16B per lane; LDS dest = wave-uniform base + lane*16
#define GLD16(gp, lp)                                                        \
  __builtin_amdgcn_global_load_lds(                                          \
      (const __attribute__((address_space(1))) unsigned int*)(gp),           \
      (__attribute__((address_space(3))) unsigned int*)(lp), 16, 0, 0)

// --------------------------------------------------------------------------
// Dtype detection (even-indexed ushorts of true bf16 N(0,1) are ~100% in
// [1e-8, 64]; f32-as-bf16 mantissa halves are ~13%).
// --------------------------------------------------------------------------
__global__ __launch_bounds__(64) void k_detect(const unsigned short* x,
                                               const unsigned short* w,
                                               const unsigned short* s,
                                               const unsigned short* v) {
  const unsigned short* ptrs[4] = {x, w, s, v};
  const int l = threadIdx.x;
  #pragma unroll
  for (int i = 0; i < 4; ++i) {
    const unsigned short u = ptrs[i][2 * l];
    const float a = fabsf(bf2f(u));
    const int good = (u == 0) || (a >= 1e-8f && a <= 64.0f);
    const unsigned long long m = __ballot(good);
    if (l == 0) g_isf32[i] = (__popcll(m) < 45) ? 1 : 0;
  }
}

// Materialize g_x in PLANAR layout: col cp<32 -> x[cp];
// cp = 32 + i*32 + u  ->  x[32 + u*3 + i].  (both dtypes)
__global__ __launch_bounds__(256) void k_convx(const void* xin) {
  const int t = blockIdx.x * 256 + threadIdx.x;
  const int n = t >> 4;
  const int cp0 = (t & 15) * 8;
  const size_t rb = (size_t)n * 128;
  short8 o;
  if (g_isf32[0]) {
    const float* xf = (const float*)xin;
    #pragma unroll
    for (int j = 0; j < 8; ++j) {
      const int cp = cp0 + j;
      const int src = cp < 32 ? cp : 32 + ((cp - 32) & 31) * 3 + ((cp - 32) >> 5);
      o[j] = (short)f2bf(xf[rb + src]);
    }
  } else {
    const unsigned short* xb = (const unsigned short*)xin;
    #pragma unroll
    for (int j = 0; j < 8; ++j) {
      const int cp = cp0 + j;
      const int src = cp < 32 ? cp : 32 + ((cp - 32) & 31) * 3 + ((cp - 32) >> 5);
      o[j] = (short)xb[rb + src];
    }
  }
  *(short8*)(&g_x[rb + cp0]) = o;
}

// --------------------------------------------------------------------------
// Block-sparse packed kernel, planar basis, Kvs input-folded.
// 12 blocks of 512 ush per ko:
//   blk 0..1  : Kss = c*Wa (+center wscs)
//   blk 2..3  : cs*Wd UNSCALED (consumed with xvY = sum_i y_i*xv_i)
//   blk 4..9  : Ksv_k = c*Wb*y_k (k=(blk-4)>>1)
//   blk 10..11: shared vv = c*Wc (+center wscv)
// ush[(blk*64+lane)*8+t] = Block[u=(lane>>4)*8+t][w=(blk&1)*16+(lane&15)].
// Also writes g_y[koff] = (Y1v0,Y1v1,Y1v2,0). Self-conn at koff==62 (y=0
// there, so the folded Kvs term correctly vanishes).
// --------------------------------------------------------------------------
__global__ __launch_bounds__(256) void gen_kern(const void* __restrict__ weight,
                                                const void* __restrict__ wscs,
                                                const void* __restrict__ wscv) {
  __shared__ float W[4][32][32];
  __shared__ float embs[5];
  const int wf = g_isf32[1], sf = g_isf32[2], vf = g_isf32[3];
  const int koff = blockIdx.x;
  const int tid = threadIdx.x;
  const int xi = koff % 5, yi = (koff / 5) % 5, zi = koff / 25;
  const float lx = (float)(xi - 2), ly = (float)(yi - 2), lz = (float)(zi - 2);
  const float nrm = sqrtf(lx*lx + ly*ly + lz*lz);
  if (tid < 5) {
    const float step = 2.5f / 6.0f;
    const float vb = step * (float)(tid + 1);
    const float d = (nrm - vb) / step;
    float e = 0.0f;
    if (fabsf(d) < 1.0f) {
      float ds = fminf(fmaxf(d, -1.0f + 1e-6f), 1.0f - 1e-6f);
      e = 1.14136f * expf(2.0f - 1.0f/(1.0f + ds) - 1.0f/(1.0f - ds));
    }
    embs[tid] = e;
  }
  __syncthreads();
  float* Wf = &W[0][0][0];
  for (int m = tid; m < 4096; m += 256) {
    float s = 0.0f;
    #pragma unroll
    for (int b = 0; b < 5; ++b) s += embs[b] * rdf(weight, b*4096 + m, wf);
    Wf[m] = s * (1.0f / 125.0f);
  }
  __syncthreads();
  const float invn = (nrm > 0.0f) ? 1.0f / nrm : 0.0f;
  const float s3 = 1.7320508075688772f;
  const float Y1v0 = s3 * ly * invn;
  const float Y1v1 = s3 * lz * invn;
  const float Y1v2 = s3 * lx * invn;
  const float c  = 0.125f;
  const float cs = 0.125f / s3;
  const bool center = (koff == 62);
  const float inv = 0.17677669529663687f;  // 1/sqrt(32)
  if (tid == 0) {
    g_y[koff][0] = Y1v0; g_y[koff][1] = Y1v1; g_y[koff][2] = Y1v2; g_y[koff][3] = 0.0f;
  }
  for (int p = tid; p < KTILE; p += 256) {
    const int t = p & 7;
    const int lane = (p >> 3) & 63;
    const int blk = p >> 9;                      // 0..11
    const int u = ((lane >> 4) << 3) + t;        // 0..31
    const int w = (blk & 1) * 16 + (lane & 15);  // 0..31
    float val;
    if (blk < 2) {
      val = c * W[0][u][w];
      if (center) val += inv * rdf(wscs, u*32 + w, sf);
    } else if (blk < 4) {
      val = cs * W[3][u][w];                     // unscaled Kvs base
    } else if (blk < 10) {
      const int k = (blk - 4) >> 1;
      const float y = (k == 0) ? Y1v0 : ((k == 1) ? Y1v1 : Y1v2);
      val = c * W[1][u][w] * y;
    } else {
      val = c * W[2][u][w];
      if (center) val += inv * rdf(wscv, u*32 + w, vf);
    }
    g_kern[koff * KTILE + p] = f2bf(val);
  }
}

// --------------------------------------------------------------------------
// Main conv: 512 WGs x 512 thr (8 waves), 2 blocks/CU, 16 waves/CU.
// Wave = 32 dsts x 128 cols. TWO ko per barrier (pair-slots of 2x12KB).
// Kvs input-fold: xvY = sum_i y_i*xv_i (VALU, mid-section) replaces the
// 3 y-scaled Kvs blocks -> 12 LDS b128 reads/wave/ko (was 16), 32 MFMA
// (was 40). Progressive a-refills after each slot's last use. Exec-masked
// gathers, nt idx loads, act-gating, symmetric 3xGLD16 pair staging.
// --------------------------------------------------------------------------
__global__ __launch_bounds__(512, 4) void conv_main(
    const int* __restrict__ nidx,
    void* __restrict__ out)
{
  __shared__ __align__(16) unsigned short Buf[32768];  // 64 KB = 2 pair-slots + epi
  const int of32 = g_isf32[0];
  const char* xb = (const char*)g_x;
  const int tid = threadIdx.x;
  const int wv = tid >> 6;        // 0..7
  const int l  = tid & 63;
  const int lr = l & 15;
  const int lk = l >> 4;
  const int m0 = blockIdx.x * 256 + wv * 32;   // wave's 32 dsts

  f32x4 acc[2][8];
  #pragma unroll
  for (int i = 0; i < 2; ++i)
    #pragma unroll
    for (int j = 0; j < 8; ++j) acc[i][j] = (f32x4)0.0f;

  {  // prologue: reg-stage tiles 0+1 (24 KB = 12288 ush) into slot 0
    const unsigned short* s = g_kern + tid*8;
    short8 p[3];
    #pragma unroll
    for (int c = 0; c < 3; ++c) p[c] = *(const short8*)(s + c*4096);
    #pragma unroll
    for (int c = 0; c < 3; ++c) *(short8*)(&Buf[tid*8 + c*4096]) = p[c];
  }

  // prologue: ko=0 gathers + idx(1)
  bool actc[2];
  int iK1[2], iK2[2], iK3[2];
  short8 a[4][2];
  {
    const int* ip = nidx + m0;
    #pragma unroll
    for (int mt = 0; mt < 2; ++mt) {
      const int idx = __builtin_nontemporal_load(ip + mt*16 + lr);
      const bool vl = (unsigned)idx < (unsigned)NPTS;
      actc[mt] = __any(vl);
      const unsigned uo = (unsigned)idx * 256u + (unsigned)lk * 16u;
      #pragma unroll
      for (int kb = 0; kb < 4; ++kb) {
        short8 v = (short8)(short)0;
        if (vl) v = *(const short8*)(xb + uo + kb*64);
        a[kb][mt] = v;
      }
    }
    const int* ip1 = nidx + (size_t)NPTS + m0;
    #pragma unroll
    for (int mt = 0; mt < 2; ++mt)
      iK1[mt] = __builtin_nontemporal_load(ip1 + mt*16 + lr);
  }
  __syncthreads();

  // one ko section: tile at Buf[BB], y from g_y[KOY], refill for RIDX if DOREF
#define KO_SECTION(BB, KOY, RIDX, DOREF)                                      \
  {                                                                           \
    const unsigned short* B = &Buf[(BB)];                                     \
    const float y0 = g_y[(KOY)][0], y1 = g_y[(KOY)][1], y2 = g_y[(KOY)][2];   \
    bool vln[2]; bool actn[2]; unsigned uoffn[2];                             \
    if (DOREF) {                                                              \
      _Pragma("unroll")                                                       \
      for (int mt = 0; mt < 2; ++mt) {                                        \
        vln[mt]  = (unsigned)(RIDX)[mt] < (unsigned)NPTS;                     \
        actn[mt] = __any(vln[mt]);                                            \
        uoffn[mt] = (unsigned)(RIDX)[mt] * 256u + (unsigned)lk * 16u;         \
      }                                                                       \
    }                                                                         \
    const bool anyact = actc[0] || actc[1];                                   \
    if (anyact) {                                                             \
      /* Kss (blk0..1, a[0]) */                                               \
      {                                                                       \
        const short8 bs0 = *(const short8*)(&B[((0)*64 + l)*8]);              \
        const short8 bs1 = *(const short8*)(&B[((1)*64 + l)*8]);              \
        _Pragma("unroll")                                                     \
        for (int mt = 0; mt < 2; ++mt) {                                      \
          if (actc[mt]) {                                                     \
            acc[mt][0] = __builtin_amdgcn_mfma_f32_16x16x32_bf16(             \
                a[0][mt], bs0, acc[mt][0], 0, 0, 0);                          \
            acc[mt][1] = __builtin_amdgcn_mfma_f32_16x16x32_bf16(             \
                a[0][mt], bs1, acc[mt][1], 0, 0, 0);                          \
          }                                                                   \
        }                                                                     \
      }                                                                       \
      /* Ksv (blk4..9, a[0] last use) */                                      \
      _Pragma("unroll")                                                       \
      for (int i = 0; i < 3; ++i) {                                           \
        const short8 bsv0 = *(const short8*)(&B[((4 + i*2)*64 + l)*8]);       \
        const short8 bsv1 = *(const short8*)(&B[((5 + i*2)*64 + l)*8]);       \
        _Pragma("unroll")                                                     \
        for (int mt = 0; mt < 2; ++mt) {                                      \
          if (actc[mt]) {                                                     \
            acc[mt][2 + 2*i] = __builtin_amdgcn_mfma_f32_16x16x32_bf16(       \
                a[0][mt], bsv0, acc[mt][2 + 2*i], 0, 0, 0);                   \
            acc[mt][3 + 2*i] = __builtin_amdgcn_mfma_f32_16x16x32_bf16(       \
                a[0][mt], bsv1, acc[mt][3 + 2*i], 0, 0, 0);                   \
          }                                                                   \
        }                                                                     \
      }                                                                       \
    }                                                                         \
    if (DOREF) {  /* a[0] dead after Ksv: refill now */                       \
      _Pragma("unroll")                                                       \
      for (int mt = 0; mt < 2; ++mt) {                                        \
        short8 v = (short8)(short)0;                                          \
        if (vln[mt]) v = *(const short8*)(xb + uoffn[mt]);                    \
        a[0][mt] = v;                                                         \
      }                                                                       \
    }                                                                         \
    if (anyact) {                                                             \
      /* fold: xvY = y0*xv0 + y1*xv1 + y2*xv2 (per-lane VALU) */              \
      const short8 bw0 = *(const short8*)(&B[((2)*64 + l)*8]);                \
      const short8 bw1 = *(const short8*)(&B[((3)*64 + l)*8]);                \
      _Pragma("unroll")                                                       \
      for (int mt = 0; mt < 2; ++mt) {                                        \
        if (actc[mt]) {                                                       \
          short8 xvY;                                                         \
          _Pragma("unroll")                                                   \
          for (int jj = 0; jj < 8; ++jj) {                                    \
            const float f = y0 * bf2f((unsigned short)a[1][mt][jj])           \
                          + y1 * bf2f((unsigned short)a[2][mt][jj])           \
                          + y2 * bf2f((unsigned short)a[3][mt][jj]);          \
            xvY[jj] = (short)f2bf(f);                                         \
          }                                                                   \
          acc[mt][0] = __builtin_amdgcn_mfma_f32_16x16x32_bf16(               \
              xvY, bw0, acc[mt][0], 0, 0, 0);                                 \
          acc[mt][1] = __builtin_amdgcn_mfma_f32_16x16x32_bf16(               \
              xvY, bw1, acc[mt][1], 0, 0, 0);                                 \
        }                                                                     \
      }                                                                       \
    }                                                                         \
    {                                                                         \
      const short8 bv0 = anyact ? *(const short8*)(&B[(10*64 + l)*8])         \
                                : (short8)(short)0;                           \
      const short8 bv1 = anyact ? *(const short8*)(&B[(11*64 + l)*8])         \
                                : (short8)(short)0;                           \
      _Pragma("unroll")                                                       \
      for (int i = 0; i < 3; ++i) {                                           \
        if (anyact) {                                                         \
          _Pragma("unroll")                                                   \
          for (int mt = 0; mt < 2; ++mt) {                                    \
            if (actc[mt]) {                                                   \
              acc[mt][2 + 2*i] = __builtin_amdgcn_mfma_f32_16x16x32_bf16(     \
                  a[1 + i][mt], bv0, acc[mt][2 + 2*i], 0, 0, 0);              \
              acc[mt][3 + 2*i] = __builtin_amdgcn_mfma_f32_16x16x32_bf16(     \
                  a[1 + i][mt], bv1, acc[mt][3 + 2*i], 0, 0, 0);              \
            }                                                                 \
          }                                                                   \
        }                                                                     \
        if (DOREF) {  /* a[1+i] dead after vv_i: refill now */                \
          _Pragma("unroll")                                                   \
          for (int mt = 0; mt < 2; ++mt) {                                    \
            short8 v = (short8)(short)0;                                      \
            if (vln[mt]) v = *(const short8*)(xb + uoffn[mt] + (1 + i)*64);   \
            a[1 + i][mt] = v;                                                 \
          }                                                                   \
        }                                                                     \
      }                                                                       \
    }                                                                         \
    if (DOREF) {                                                              \
      _Pragma("unroll")                                                       \
      for (int mt = 0; mt < 2; ++mt) actc[mt] = actn[mt];                     \
    }                                                                         \
  }

  for (int j = 0; j < 62; ++j) {
    const int cur = (j & 1) * 12288;        // compute pair-slot base (ush)
    const int sb  = 12288 - cur;            // stage pair-slot base
    const bool h3 = (j < 61);

    // stage tiles 2j+2 (+ 2j+3) into the other slot
    if (h3) {  // pair: 24 KB contiguous, symmetric 3 rounds
      const unsigned short* s0 = g_kern + (size_t)(2*j + 2) * KTILE;
      #pragma unroll
      for (int c = 0; c < 3; ++c)
        GLD16(s0 + c*4096 + wv*512 + l*8, &Buf[sb + c*4096 + wv*512]);
    } else {   // last: tile 124 only (12 KB)
      const unsigned short* s0 = g_kern + (size_t)124 * KTILE;
      GLD16(s0 + wv*512 + l*8, &Buf[sb + wv*512]);
      if (wv < 4) GLD16(s0 + 4096 + wv*512 + l*8, &Buf[sb + 4096 + wv*512]);
    }
    // prefetch indices 2j+2, 2j+3
    {
      const int* ip2 = nidx + (size_t)(2*j + 2) * NPTS + m0;
      #pragma unroll
      for (int mt = 0; mt < 2; ++mt)
        iK2[mt] = __builtin_nontemporal_load(ip2 + mt*16 + lr);
      if (h3) {
        const int* ip3 = nidx + (size_t)(2*j + 3) * NPTS + m0;
        #pragma unroll
        for (int mt = 0; mt < 2; ++mt)
          iK3[mt] = __builtin_nontemporal_load(ip3 + mt*16 + lr);
      }
    }

    KO_SECTION(cur,        2*j,     iK1, true)   // k0 = 2j, refill -> k1
    KO_SECTION(cur + 6144, 2*j + 1, iK2, true)   // k1 = 2j+1, refill -> 2j+2

    #pragma unroll
    for (int mt = 0; mt < 2; ++mt) iK1[mt] = iK3[mt];
    __syncthreads();
  }

  // tail: ko = 124 (staged at j=61 into slot 0; a[]/actc ready)
  KO_SECTION(0, 124, iK1, false)
  __syncthreads();

#undef KO_SECTION

  // epilogue: planar acc -> ORIGINAL interleaved columns.
  // q<2: oc = q*16+lr. q>=2: i=(q-2)>>1, h=(q-2)&1 -> oc = 32+(h*16+lr)*3+i.
  if (of32) {
    float* of = (float*)out;
    #pragma unroll
    for (int mt = 0; mt < 2; ++mt)
      #pragma unroll
      for (int q = 0; q < 8; ++q) {
        const int oc = (q < 2) ? (q*16 + lr)
                               : 32 + (((q - 2) & 1)*16 + lr)*3 + ((q - 2) >> 1);
        #pragma unroll
        for (int r = 0; r < 4; ++r)
          __builtin_nontemporal_store(
              acc[mt][q][r],
              &of[(size_t)(m0 + mt*16 + lk*4 + r) * 128 + oc]);
      }
  } else {
    // block-wide LDS bounce (XOR-swizzled, un-permutes), coalesced nt stores
    unsigned short* eb = &Buf[0];   // 64 KB = 256 rows x 128 cols
    #pragma unroll
    for (int mt = 0; mt < 2; ++mt)
      #pragma unroll
      for (int q = 0; q < 8; ++q) {
        const int oc = (q < 2) ? (q*16 + lr)
                               : 32 + (((q - 2) & 1)*16 + lr)*3 + ((q - 2) >> 1);
        #pragma unroll
        for (int r = 0; r < 4; ++r) {
          const int row = wv*32 + mt*16 + lk*4 + r;    // 0..255 local
          eb[row*128 + (oc ^ ((row & 7) << 3))] = f2bf(acc[mt][q][r]);
        }
      }
    __syncthreads();
    unsigned short* ob = (unsigned short*)out;
    const int row = tid >> 1;
    #pragma unroll
    for (int it = 0; it < 8; ++it) {
      const int ub = (tid & 1)*64 + it*8;
      const short8 v = *(const short8*)(&eb[row*128 + (ub ^ ((row & 7) << 3))]);
      __builtin_nontemporal_store(
          v, (short8*)&ob[(size_t)(blockIdx.x*256 + row) * 128 + ub]);
    }
  }
}

extern "C" void kernel_launch(void* const* d_in, const int* in_sizes, int n_in,
                              void* d_out, int out_size, void* d_ws, size_t ws_size,
                              hipStream_t stream) {
  const void* weight = d_in[1];
  const void* wscs   = d_in[2];
  const void* wscv   = d_in[3];
  const int*  nidx   = (const int*)d_in[4];

  hipLaunchKernelGGL(k_detect, dim3(1), dim3(64), 0, stream,
                     (const unsigned short*)d_in[0], (const unsigned short*)d_in[1],
                     (const unsigned short*)d_in[2], (const unsigned short*)d_in[3]);
  hipLaunchKernelGGL(k_convx, dim3(NPTS * 128 / (256 * 8)), dim3(256), 0, stream, d_in[0]);
  hipLaunchKernelGGL(gen_kern, dim3(NOFF), dim3(256), 0, stream, weight, wscs, wscv);
  hipLaunchKernelGGL(conv_main, dim3(NPTS / 256), dim3(512), 0, stream,
                     nidx, d_out);
}

// Round 16
// 242.711 us; speedup vs baseline: 2.7570x; 2.7570x over previous
//
#include <hip/hip_runtime.h>

typedef __attribute__((ext_vector_type(8))) short short8;
typedef __attribute__((ext_vector_type(4))) float f32x4;

#define NPTS 131072
#define NOFF 125
#define KTILE 8192                 // 16 KB/offset: 16 blocks of 512 ush
#define KERN_USH (NOFF * KTILE)

__device__ int g_isf32[4];                                     // per-input f32 flag
__device__ __align__(16) unsigned short g_x[NPTS * 128 + 128]; // x, planar layout, bf16
__device__ __align__(16) unsigned short g_kern[KERN_USH + 128];

__device__ __forceinline__ float bf2f(unsigned short u) {
  unsigned int v = ((unsigned int)u) << 16;
  return __builtin_bit_cast(float, v);
}
__device__ __forceinline__ unsigned short f2bf(float f) {
  unsigned int x = __builtin_bit_cast(unsigned int, f);
  x += 0x7fffu + ((x >> 16) & 1u);
  return (unsigned short)(x >> 16);
}
__device__ __forceinline__ float rdf(const void* p, int i, int isf32) {
  return isf32 ? ((const float*)p)[i] : bf2f(((const unsigned short*)p)[i]);
}

// direct global->LDS, 16B per lane; LDS dest = wave-uniform base + lane*16
#define GLD16(gp, lp)                                                        \
  __builtin_amdgcn_global_load_lds(                                          \
      (const __attribute__((address_space(1))) unsigned int*)(gp),           \
      (__attribute__((address_space(3))) unsigned int*)(lp), 16, 0, 0)

// --------------------------------------------------------------------------
// Dtype detection (even-indexed ushorts of true bf16 N(0,1) are ~100% in
// [1e-8, 64]; f32-as-bf16 mantissa halves are ~13%).
// --------------------------------------------------------------------------
__global__ __launch_bounds__(64) void k_detect(const unsigned short* x,
                                               const unsigned short* w,
                                               const unsigned short* s,
                                               const unsigned short* v) {
  const unsigned short* ptrs[4] = {x, w, s, v};
  const int l = threadIdx.x;
  #pragma unroll
  for (int i = 0; i < 4; ++i) {
    const unsigned short u = ptrs[i][2 * l];
    const float a = fabsf(bf2f(u));
    const int good = (u == 0) || (a >= 1e-8f && a <= 64.0f);
    const unsigned long long m = __ballot(good);
    if (l == 0) g_isf32[i] = (__popcll(m) < 45) ? 1 : 0;
  }
}

// Materialize g_x in PLANAR layout: col cp<32 -> x[cp];
// cp = 32 + i*32 + u  ->  x[32 + u*3 + i].  (both dtypes)
__global__ __launch_bounds__(256) void k_convx(const void* xin) {
  const int t = blockIdx.x * 256 + threadIdx.x;
  const int n = t >> 4;
  const int cp0 = (t & 15) * 8;
  const size_t rb = (size_t)n * 128;
  short8 o;
  if (g_isf32[0]) {
    const float* xf = (const float*)xin;
    #pragma unroll
    for (int j = 0; j < 8; ++j) {
      const int cp = cp0 + j;
      const int src = cp < 32 ? cp : 32 + ((cp - 32) & 31) * 3 + ((cp - 32) >> 5);
      o[j] = (short)f2bf(xf[rb + src]);
    }
  } else {
    const unsigned short* xb = (const unsigned short*)xin;
    #pragma unroll
    for (int j = 0; j < 8; ++j) {
      const int cp = cp0 + j;
      const int src = cp < 32 ? cp : 32 + ((cp - 32) & 31) * 3 + ((cp - 32) >> 5);
      o[j] = (short)xb[rb + src];
    }
  }
  *(short8*)(&g_x[rb + cp0]) = o;
}

// --------------------------------------------------------------------------
// Block-sparse packed kernel, planar basis (R11 layout). 16 blocks of 512
// ush per ko: blk 0..7 = col-s region (kb=blk>>1, nt=blk&1): kb==0 -> Kss,
// kb==1+i -> Kvs_i. blk 8..13 = Ksv_k (k=(blk-8)>>1). blk 14..15 = shared
// vv = c*Wc. ush[(blk*64+lane)*8+t] =
// Block[u=(lane>>4)*8+t][w=(blk&1)*16+(lane&15)]. Self-conn at koff==62.
// --------------------------------------------------------------------------
__global__ __launch_bounds__(256) void gen_kern(const void* __restrict__ weight,
                                                const void* __restrict__ wscs,
                                                const void* __restrict__ wscv) {
  __shared__ float W[4][32][32];
  __shared__ float embs[5];
  const int wf = g_isf32[1], sf = g_isf32[2], vf = g_isf32[3];
  const int koff = blockIdx.x;
  const int tid = threadIdx.x;
  const int xi = koff % 5, yi = (koff / 5) % 5, zi = koff / 25;
  const float lx = (float)(xi - 2), ly = (float)(yi - 2), lz = (float)(zi - 2);
  const float nrm = sqrtf(lx*lx + ly*ly + lz*lz);
  if (tid < 5) {
    const float step = 2.5f / 6.0f;
    const float vb = step * (float)(tid + 1);
    const float d = (nrm - vb) / step;
    float e = 0.0f;
    if (fabsf(d) < 1.0f) {
      float ds = fminf(fmaxf(d, -1.0f + 1e-6f), 1.0f - 1e-6f);
      e = 1.14136f * expf(2.0f - 1.0f/(1.0f + ds) - 1.0f/(1.0f - ds));
    }
    embs[tid] = e;
  }
  __syncthreads();
  float* Wf = &W[0][0][0];
  for (int m = tid; m < 4096; m += 256) {
    float s = 0.0f;
    #pragma unroll
    for (int b = 0; b < 5; ++b) s += embs[b] * rdf(weight, b*4096 + m, wf);
    Wf[m] = s * (1.0f / 125.0f);
  }
  __syncthreads();
  const float invn = (nrm > 0.0f) ? 1.0f / nrm : 0.0f;
  const float s3 = 1.7320508075688772f;
  const float Y1v0 = s3 * ly * invn;
  const float Y1v1 = s3 * lz * invn;
  const float Y1v2 = s3 * lx * invn;
  const float c  = 0.125f;
  const float cs = 0.125f / s3;
  const bool center = (koff == 62);
  const float inv = 0.17677669529663687f;  // 1/sqrt(32)
  for (int p = tid; p < KTILE; p += 256) {
    const int t = p & 7;
    const int lane = (p >> 3) & 63;
    const int blk = p >> 9;                      // 0..15
    const int u = ((lane >> 4) << 3) + t;        // 0..31
    const int w = (blk & 1) * 16 + (lane & 15);  // 0..31
    float val;
    if (blk < 8) {
      const int kb = blk >> 1;
      if (kb == 0) {
        val = c * W[0][u][w];
        if (center) val += inv * rdf(wscs, u*32 + w, sf);
      } else {
        const int i = kb - 1;
        const float y = (i == 0) ? Y1v0 : ((i == 1) ? Y1v1 : Y1v2);
        val = cs * W[3][u][w] * y;
      }
    } else if (blk < 14) {
      const int k = (blk - 8) >> 1;
      const float y = (k == 0) ? Y1v0 : ((k == 1) ? Y1v1 : Y1v2);
      val = c * W[1][u][w] * y;
    } else {
      val = c * W[2][u][w];
      if (center) val += inv * rdf(wscv, u*32 + w, vf);
    }
    g_kern[koff * KTILE + p] = f2bf(val);
  }
}

// --------------------------------------------------------------------------
// Main conv: 512 WGs x 512 thr (8 waves), 2 blocks/CU, 16 waves/CU.
// Wave = 32 dsts x 128 cols, R11 compute exactly. TWO ko per barrier
// (2x32KB pair-slots) + progressive a-refills (after each slot's last
// use) -> the per-ko vmcnt(0)+barrier drain tax is halved and k1's
// refills are covered by register deps instead of the barrier.
// --------------------------------------------------------------------------
__global__ __launch_bounds__(512, 4) void conv_main(
    const int* __restrict__ nidx,
    void* __restrict__ out)
{
  __shared__ __align__(16) unsigned short Buf[32768];  // 64 KB = 2 pair-slots
  const int of32 = g_isf32[0];
  const char* xb = (const char*)g_x;
  const int tid = threadIdx.x;
  const int wv = tid >> 6;        // 0..7
  const int l  = tid & 63;
  const int lr = l & 15;
  const int lk = l >> 4;
  const int m0 = blockIdx.x * 256 + wv * 32;   // wave's 32 dsts

  f32x4 acc[2][8];
  #pragma unroll
  for (int i = 0; i < 2; ++i)
    #pragma unroll
    for (int j = 0; j < 8; ++j) acc[i][j] = (f32x4)0.0f;

  {  // prologue: reg-stage tiles 0+1 (32 KB) into slot 0
    const unsigned short* s = g_kern + tid*8;
    short8 p[4];
    #pragma unroll
    for (int c = 0; c < 4; ++c) p[c] = *(const short8*)(s + c*4096);
    #pragma unroll
    for (int c = 0; c < 4; ++c) *(short8*)(&Buf[tid*8 + c*4096]) = p[c];
  }

  // prologue: ko=0 gathers + idx(1)
  bool actc[2];
  int iK1[2], iK2[2], iK3[2];
  short8 a[4][2];
  {
    const int* ip = nidx + m0;
    #pragma unroll
    for (int mt = 0; mt < 2; ++mt) {
      const int idx = __builtin_nontemporal_load(ip + mt*16 + lr);
      const bool vl = (unsigned)idx < (unsigned)NPTS;
      actc[mt] = __any(vl);
      const unsigned uo = (unsigned)idx * 256u + (unsigned)lk * 16u;
      #pragma unroll
      for (int kb = 0; kb < 4; ++kb) {
        short8 v = (short8)(short)0;
        if (vl) v = *(const short8*)(xb + uo + kb*64);
        a[kb][mt] = v;
      }
    }
    const int* ip1 = nidx + (size_t)NPTS + m0;
    #pragma unroll
    for (int mt = 0; mt < 2; ++mt)
      iK1[mt] = __builtin_nontemporal_load(ip1 + mt*16 + lr);
  }
  __syncthreads();

  // one ko section: compute from tile at Buf[bb], refill a[] for RIDX (if DOREF)
#define KO_SECTION(BB, RIDX, DOREF)                                           \
  {                                                                           \
    const unsigned short* B = &Buf[(BB)];                                     \
    bool vln[2]; bool actn[2]; unsigned uoffn[2];                             \
    if (DOREF) {                                                              \
      _Pragma("unroll")                                                       \
      for (int mt = 0; mt < 2; ++mt) {                                        \
        vln[mt]  = (unsigned)(RIDX)[mt] < (unsigned)NPTS;                     \
        actn[mt] = __any(vln[mt]);                                            \
        uoffn[mt] = (unsigned)(RIDX)[mt] * 256u + (unsigned)lk * 16u;         \
      }                                                                       \
    }                                                                         \
    const bool anyact = actc[0] || actc[1];                                   \
    if (anyact) {                                                             \
      _Pragma("unroll")                                                       \
      for (int kb = 0; kb < 4; ++kb) {                                        \
        const short8 bs0 = *(const short8*)(&B[((kb*2 + 0)*64 + l)*8]);       \
        const short8 bs1 = *(const short8*)(&B[((kb*2 + 1)*64 + l)*8]);       \
        _Pragma("unroll")                                                     \
        for (int mt = 0; mt < 2; ++mt) {                                      \
          if (actc[mt]) {                                                     \
            acc[mt][0] = __builtin_amdgcn_mfma_f32_16x16x32_bf16(             \
                a[kb][mt], bs0, acc[mt][0], 0, 0, 0);                         \
            acc[mt][1] = __builtin_amdgcn_mfma_f32_16x16x32_bf16(             \
                a[kb][mt], bs1, acc[mt][1], 0, 0, 0);                         \
          }                                                                   \
        }                                                                     \
      }                                                                       \
      _Pragma("unroll")                                                       \
      for (int i = 0; i < 3; ++i) {                                           \
        const short8 bsv0 = *(const short8*)(&B[((8 + i*2)*64 + l)*8]);       \
        const short8 bsv1 = *(const short8*)(&B[((9 + i*2)*64 + l)*8]);       \
        _Pragma("unroll")                                                     \
        for (int mt = 0; mt < 2; ++mt) {                                      \
          if (actc[mt]) {                                                     \
            acc[mt][2 + 2*i] = __builtin_amdgcn_mfma_f32_16x16x32_bf16(       \
                a[0][mt], bsv0, acc[mt][2 + 2*i], 0, 0, 0);                   \
            acc[mt][3 + 2*i] = __builtin_amdgcn_mfma_f32_16x16x32_bf16(       \
                a[0][mt], bsv1, acc[mt][3 + 2*i], 0, 0, 0);                   \
          }                                                                   \
        }                                                                     \
      }                                                                       \
    }                                                                         \
    if (DOREF) {  /* a[0] dead after Ksv: refill now */                       \
      _Pragma("unroll")                                                       \
      for (int mt = 0; mt < 2; ++mt) {                                        \
        short8 v = (short8)(short)0;                                          \
        if (vln[mt]) v = *(const short8*)(xb + uoffn[mt]);                    \
        a[0][mt] = v;                                                         \
      }                                                                       \
    }                                                                         \
    {                                                                         \
      const short8 bv0 = anyact ? *(const short8*)(&B[(14*64 + l)*8])         \
                                : (short8)(short)0;                           \
      const short8 bv1 = anyact ? *(const short8*)(&B[(15*64 + l)*8])         \
                                : (short8)(short)0;                           \
      _Pragma("unroll")                                                       \
      for (int i = 0; i < 3; ++i) {                                           \
        if (anyact) {                                                         \
          _Pragma("unroll")                                                   \
          for (int mt = 0; mt < 2; ++mt) {                                    \
            if (actc[mt]) {                                                   \
              acc[mt][2 + 2*i] = __builtin_amdgcn_mfma_f32_16x16x32_bf16(     \
                  a[1 + i][mt], bv0, acc[mt][2 + 2*i], 0, 0, 0);              \
              acc[mt][3 + 2*i] = __builtin_amdgcn_mfma_f32_16x16x32_bf16(     \
                  a[1 + i][mt], bv1, acc[mt][3 + 2*i], 0, 0, 0);              \
            }                                                                 \
          }                                                                   \
        }                                                                     \
        if (DOREF) {  /* a[1+i] dead after vv_i: refill now */                \
          _Pragma("unroll")                                                   \
          for (int mt = 0; mt < 2; ++mt) {                                    \
            short8 v = (short8)(short)0;                                      \
            if (vln[mt]) v = *(const short8*)(xb + uoffn[mt] + (1 + i)*64);   \
            a[1 + i][mt] = v;                                                 \
          }                                                                   \
        }                                                                     \
      }                                                                       \
    }                                                                         \
    if (DOREF) {                                                              \
      _Pragma("unroll")                                                       \
      for (int mt = 0; mt < 2; ++mt) actc[mt] = actn[mt];                     \
    }                                                                         \
  }

  for (int j = 0; j < 62; ++j) {
    const int cur = j & 1;
    const int sb  = (cur ^ 1) * 16384;      // stage slot (ush index)
    const bool h3 = (j < 61);

    // stage tiles 2j+2 (and 2j+3) into the other slot
    {
      const unsigned short* s0 = g_kern + (size_t)(2*j + 2) * KTILE;
      GLD16(s0 + wv*512 + l*8,        &Buf[sb + wv*512]);
      GLD16(s0 + 4096 + wv*512 + l*8, &Buf[sb + 4096 + wv*512]);
      if (h3) {
        const unsigned short* s1 = g_kern + (size_t)(2*j + 3) * KTILE;
        GLD16(s1 + wv*512 + l*8,        &Buf[sb + 8192 + wv*512]);
        GLD16(s1 + 4096 + wv*512 + l*8, &Buf[sb + 12288 + wv*512]);
      }
    }
    // prefetch indices 2j+2, 2j+3
    {
      const int* ip2 = nidx + (size_t)(2*j + 2) * NPTS + m0;
      #pragma unroll
      for (int mt = 0; mt < 2; ++mt)
        iK2[mt] = __builtin_nontemporal_load(ip2 + mt*16 + lr);
      if (h3) {
        const int* ip3 = nidx + (size_t)(2*j + 3) * NPTS + m0;
        #pragma unroll
        for (int mt = 0; mt < 2; ++mt)
          iK3[mt] = __builtin_nontemporal_load(ip3 + mt*16 + lr);
      }
    }

    KO_SECTION(cur * 16384,        iK1, true)   // k0 = 2j, refill -> k1
    KO_SECTION(cur * 16384 + 8192, iK2, true)   // k1 = 2j+1, refill -> 2j+2

    #pragma unroll
    for (int mt = 0; mt < 2; ++mt) iK1[mt] = iK3[mt];
    __syncthreads();
  }

  // tail: ko = 124 (tile staged at j=61 into slot 0; a[]/actc ready)
  KO_SECTION(0, iK1, false)
  __syncthreads();

#undef KO_SECTION

  // epilogue: planar acc -> ORIGINAL interleaved columns.
  // q<2: oc = q*16+lr. q>=2: i=(q-2)>>1, h=(q-2)&1 -> oc = 32+(h*16+lr)*3+i.
  if (of32) {
    float* of = (float*)out;
    #pragma unroll
    for (int mt = 0; mt < 2; ++mt)
      #pragma unroll
      for (int q = 0; q < 8; ++q) {
        const int oc = (q < 2) ? (q*16 + lr)
                               : 32 + (((q - 2) & 1)*16 + lr)*3 + ((q - 2) >> 1);
        #pragma unroll
        for (int r = 0; r < 4; ++r)
          __builtin_nontemporal_store(
              acc[mt][q][r],
              &of[(size_t)(m0 + mt*16 + lk*4 + r) * 128 + oc]);
      }
  } else {
    // block-wide LDS bounce (XOR-swizzled, un-permutes), coalesced nt stores
    unsigned short* eb = &Buf[0];   // 64 KB = 256 rows x 128 cols
    #pragma unroll
    for (int mt = 0; mt < 2; ++mt)
      #pragma unroll
      for (int q = 0; q < 8; ++q) {
        const int oc = (q < 2) ? (q*16 + lr)
                               : 32 + (((q - 2) & 1)*16 + lr)*3 + ((q - 2) >> 1);
        #pragma unroll
        for (int r = 0; r < 4; ++r) {
          const int row = wv*32 + mt*16 + lk*4 + r;    // 0..255 local
          eb[row*128 + (oc ^ ((row & 7) << 3))] = f2bf(acc[mt][q][r]);
        }
      }
    __syncthreads();
    unsigned short* ob = (unsigned short*)out;
    const int row = tid >> 1;
    #pragma unroll
    for (int it = 0; it < 8; ++it) {
      const int ub = (tid & 1)*64 + it*8;
      const short8 v = *(const short8*)(&eb[row*128 + (ub ^ ((row & 7) << 3))]);
      __builtin_nontemporal_store(
          v, (short8*)&ob[(size_t)(blockIdx.x*256 + row) * 128 + ub]);
    }
  }
}

extern "C" void kernel_launch(void* const* d_in, const int* in_sizes, int n_in,
                              void* d_out, int out_size, void* d_ws, size_t ws_size,
                              hipStream_t stream) {
  const void* weight = d_in[1];
  const void* wscs   = d_in[2];
  const void* wscv   = d_in[3];
  const int*  nidx   = (const int*)d_in[4];

  hipLaunchKernelGGL(k_detect, dim3(1), dim3(64), 0, stream,
                     (const unsigned short*)d_in[0], (const unsigned short*)d_in[1],
                     (const unsigned short*)d_in[2], (const unsigned short*)d_in[3]);
  hipLaunchKernelGGL(k_convx, dim3(NPTS * 128 / (256 * 8)), dim3(256), 0, stream, d_in[0]);
  hipLaunchKernelGGL(gen_kern, dim3(NOFF), dim3(256), 0, stream, weight, wscs, wscv);
  hipLaunchKernelGGL(conv_main, dim3(NPTS / 256), dim3(512), 0, stream,
                     nidx, d_out);
}

// Round 17
// 242.694 us; speedup vs baseline: 2.7572x; 1.0001x over previous
//
#include <hip/hip_runtime.h>

typedef __attribute__((ext_vector_type(8))) short short8;
typedef __attribute__((ext_vector_type(4))) float f32x4;

#define NPTS 131072
#define NOFF 125
#define KTILE 8192                 // 16 KB/offset: 16 blocks of 512 ush
#define KERN_USH (NOFF * KTILE)

__device__ int g_isf32[4];                                     // per-input f32 flag
__device__ __align__(16) unsigned short g_x[NPTS * 128 + 128]; // x, planar layout, bf16
__device__ __align__(16) unsigned short g_kern[KERN_USH + 128];

__device__ __forceinline__ float bf2f(unsigned short u) {
  unsigned int v = ((unsigned int)u) << 16;
  return __builtin_bit_cast(float, v);
}
__device__ __forceinline__ unsigned short f2bf(float f) {
  unsigned int x = __builtin_bit_cast(unsigned int, f);
  x += 0x7fffu + ((x >> 16) & 1u);
  return (unsigned short)(x >> 16);
}
__device__ __forceinline__ float rdf(const void* p, int i, int isf32) {
  return isf32 ? ((const float*)p)[i] : bf2f(((const unsigned short*)p)[i]);
}

// direct global->LDS, 16B per lane; LDS dest = wave-uniform base + lane*16
#define GLD16(gp, lp)                                                        \
  __builtin_amdgcn_global_load_lds(                                          \
      (const __attribute__((address_space(1))) unsigned int*)(gp),           \
      (__attribute__((address_space(3))) unsigned int*)(lp), 16, 0, 0)

// --------------------------------------------------------------------------
// Dtype detection (even-indexed ushorts of true bf16 N(0,1) are ~100% in
// [1e-8, 64]; f32-as-bf16 mantissa halves are ~13%).
// --------------------------------------------------------------------------
__global__ __launch_bounds__(64) void k_detect(const unsigned short* x,
                                               const unsigned short* w,
                                               const unsigned short* s,
                                               const unsigned short* v) {
  const unsigned short* ptrs[4] = {x, w, s, v};
  const int l = threadIdx.x;
  #pragma unroll
  for (int i = 0; i < 4; ++i) {
    const unsigned short u = ptrs[i][2 * l];
    const float a = fabsf(bf2f(u));
    const int good = (u == 0) || (a >= 1e-8f && a <= 64.0f);
    const unsigned long long m = __ballot(good);
    if (l == 0) g_isf32[i] = (__popcll(m) < 45) ? 1 : 0;
  }
}

// Materialize g_x in PLANAR layout: col cp<32 -> x[cp];
// cp = 32 + i*32 + u  ->  x[32 + u*3 + i].  (both dtypes)
__global__ __launch_bounds__(256) void k_convx(const void* xin) {
  const int t = blockIdx.x * 256 + threadIdx.x;
  const int n = t >> 4;
  const int cp0 = (t & 15) * 8;
  const size_t rb = (size_t)n * 128;
  short8 o;
  if (g_isf32[0]) {
    const float* xf = (const float*)xin;
    #pragma unroll
    for (int j = 0; j < 8; ++j) {
      const int cp = cp0 + j;
      const int src = cp < 32 ? cp : 32 + ((cp - 32) & 31) * 3 + ((cp - 32) >> 5);
      o[j] = (short)f2bf(xf[rb + src]);
    }
  } else {
    const unsigned short* xb = (const unsigned short*)xin;
    #pragma unroll
    for (int j = 0; j < 8; ++j) {
      const int cp = cp0 + j;
      const int src = cp < 32 ? cp : 32 + ((cp - 32) & 31) * 3 + ((cp - 32) >> 5);
      o[j] = (short)xb[rb + src];
    }
  }
  *(short8*)(&g_x[rb + cp0]) = o;
}

// --------------------------------------------------------------------------
// Block-sparse packed kernel, planar basis (R11 layout). 16 blocks of 512
// ush per ko: blk 0..7 = col-s region (kb=blk>>1, nt=blk&1): kb==0 -> Kss,
// kb==1+i -> Kvs_i. blk 8..13 = Ksv_k (k=(blk-8)>>1). blk 14..15 = shared
// vv = c*Wc. ush[(blk*64+lane)*8+t] =
// Block[u=(lane>>4)*8+t][w=(blk&1)*16+(lane&15)]. Self-conn at koff==62.
// --------------------------------------------------------------------------
__global__ __launch_bounds__(256) void gen_kern(const void* __restrict__ weight,
                                                const void* __restrict__ wscs,
                                                const void* __restrict__ wscv) {
  __shared__ float W[4][32][32];
  __shared__ float embs[5];
  const int wf = g_isf32[1], sf = g_isf32[2], vf = g_isf32[3];
  const int koff = blockIdx.x;
  const int tid = threadIdx.x;
  const int xi = koff % 5, yi = (koff / 5) % 5, zi = koff / 25;
  const float lx = (float)(xi - 2), ly = (float)(yi - 2), lz = (float)(zi - 2);
  const float nrm = sqrtf(lx*lx + ly*ly + lz*lz);
  if (tid < 5) {
    const float step = 2.5f / 6.0f;
    const float vb = step * (float)(tid + 1);
    const float d = (nrm - vb) / step;
    float e = 0.0f;
    if (fabsf(d) < 1.0f) {
      float ds = fminf(fmaxf(d, -1.0f + 1e-6f), 1.0f - 1e-6f);
      e = 1.14136f * expf(2.0f - 1.0f/(1.0f + ds) - 1.0f/(1.0f - ds));
    }
    embs[tid] = e;
  }
  __syncthreads();
  float* Wf = &W[0][0][0];
  for (int m = tid; m < 4096; m += 256) {
    float s = 0.0f;
    #pragma unroll
    for (int b = 0; b < 5; ++b) s += embs[b] * rdf(weight, b*4096 + m, wf);
    Wf[m] = s * (1.0f / 125.0f);
  }
  __syncthreads();
  const float invn = (nrm > 0.0f) ? 1.0f / nrm : 0.0f;
  const float s3 = 1.7320508075688772f;
  const float Y1v0 = s3 * ly * invn;
  const float Y1v1 = s3 * lz * invn;
  const float Y1v2 = s3 * lx * invn;
  const float c  = 0.125f;
  const float cs = 0.125f / s3;
  const bool center = (koff == 62);
  const float inv = 0.17677669529663687f;  // 1/sqrt(32)
  for (int p = tid; p < KTILE; p += 256) {
    const int t = p & 7;
    const int lane = (p >> 3) & 63;
    const int blk = p >> 9;                      // 0..15
    const int u = ((lane >> 4) << 3) + t;        // 0..31
    const int w = (blk & 1) * 16 + (lane & 15);  // 0..31
    float val;
    if (blk < 8) {
      const int kb = blk >> 1;
      if (kb == 0) {
        val = c * W[0][u][w];
        if (center) val += inv * rdf(wscs, u*32 + w, sf);
      } else {
        const int i = kb - 1;
        const float y = (i == 0) ? Y1v0 : ((i == 1) ? Y1v1 : Y1v2);
        val = cs * W[3][u][w] * y;
      }
    } else if (blk < 14) {
      const int k = (blk - 8) >> 1;
      const float y = (k == 0) ? Y1v0 : ((k == 1) ? Y1v1 : Y1v2);
      val = c * W[1][u][w] * y;
    } else {
      val = c * W[2][u][w];
      if (center) val += inv * rdf(wscv, u*32 + w, vf);
    }
    g_kern[koff * KTILE + p] = f2bf(val);
  }
}

// --------------------------------------------------------------------------
// Main conv: 512 WGs x 512 thr (8 waves), 2 blocks/CU, 16 waves/CU.
// Wave = 32 dsts x 128 cols, R14 structure exactly (2 ko/barrier,
// progressive refills). Added: T5 s_setprio(1) around MFMA clusters,
// dropped to 0 around gather-issue regions (role-diverse waves: 2
// independent blocks/CU + act-divergence give the scheduler something
// to arbitrate).
// --------------------------------------------------------------------------
__global__ __launch_bounds__(512, 4) void conv_main(
    const int* __restrict__ nidx,
    void* __restrict__ out)
{
  __shared__ __align__(16) unsigned short Buf[32768];  // 64 KB = 2 pair-slots
  const int of32 = g_isf32[0];
  const char* xb = (const char*)g_x;
  const int tid = threadIdx.x;
  const int wv = tid >> 6;        // 0..7
  const int l  = tid & 63;
  const int lr = l & 15;
  const int lk = l >> 4;
  const int m0 = blockIdx.x * 256 + wv * 32;   // wave's 32 dsts

  f32x4 acc[2][8];
  #pragma unroll
  for (int i = 0; i < 2; ++i)
    #pragma unroll
    for (int j = 0; j < 8; ++j) acc[i][j] = (f32x4)0.0f;

  {  // prologue: reg-stage tiles 0+1 (32 KB) into slot 0
    const unsigned short* s = g_kern + tid*8;
    short8 p[4];
    #pragma unroll
    for (int c = 0; c < 4; ++c) p[c] = *(const short8*)(s + c*4096);
    #pragma unroll
    for (int c = 0; c < 4; ++c) *(short8*)(&Buf[tid*8 + c*4096]) = p[c];
  }

  // prologue: ko=0 gathers + idx(1)
  bool actc[2];
  int iK1[2], iK2[2], iK3[2];
  short8 a[4][2];
  {
    const int* ip = nidx + m0;
    #pragma unroll
    for (int mt = 0; mt < 2; ++mt) {
      const int idx = __builtin_nontemporal_load(ip + mt*16 + lr);
      const bool vl = (unsigned)idx < (unsigned)NPTS;
      actc[mt] = __any(vl);
      const unsigned uo = (unsigned)idx * 256u + (unsigned)lk * 16u;
      #pragma unroll
      for (int kb = 0; kb < 4; ++kb) {
        short8 v = (short8)(short)0;
        if (vl) v = *(const short8*)(xb + uo + kb*64);
        a[kb][mt] = v;
      }
    }
    const int* ip1 = nidx + (size_t)NPTS + m0;
    #pragma unroll
    for (int mt = 0; mt < 2; ++mt)
      iK1[mt] = __builtin_nontemporal_load(ip1 + mt*16 + lr);
  }
  __syncthreads();

  // one ko section: compute from tile at Buf[bb], refill a[] for RIDX (if DOREF)
#define KO_SECTION(BB, RIDX, DOREF)                                           \
  {                                                                           \
    const unsigned short* B = &Buf[(BB)];                                     \
    bool vln[2]; bool actn[2]; unsigned uoffn[2];                             \
    if (DOREF) {                                                              \
      _Pragma("unroll")                                                       \
      for (int mt = 0; mt < 2; ++mt) {                                        \
        vln[mt]  = (unsigned)(RIDX)[mt] < (unsigned)NPTS;                     \
        actn[mt] = __any(vln[mt]);                                            \
        uoffn[mt] = (unsigned)(RIDX)[mt] * 256u + (unsigned)lk * 16u;         \
      }                                                                       \
    }                                                                         \
    const bool anyact = actc[0] || actc[1];                                   \
    if (anyact) {                                                             \
      __builtin_amdgcn_s_setprio(1);                                          \
      _Pragma("unroll")                                                       \
      for (int kb = 0; kb < 4; ++kb) {                                        \
        const short8 bs0 = *(const short8*)(&B[((kb*2 + 0)*64 + l)*8]);       \
        const short8 bs1 = *(const short8*)(&B[((kb*2 + 1)*64 + l)*8]);       \
        _Pragma("unroll")                                                     \
        for (int mt = 0; mt < 2; ++mt) {                                      \
          if (actc[mt]) {                                                     \
            acc[mt][0] = __builtin_amdgcn_mfma_f32_16x16x32_bf16(             \
                a[kb][mt], bs0, acc[mt][0], 0, 0, 0);                         \
            acc[mt][1] = __builtin_amdgcn_mfma_f32_16x16x32_bf16(             \
                a[kb][mt], bs1, acc[mt][1], 0, 0, 0);                         \
          }                                                                   \
        }                                                                     \
      }                                                                       \
      _Pragma("unroll")                                                       \
      for (int i = 0; i < 3; ++i) {                                           \
        const short8 bsv0 = *(const short8*)(&B[((8 + i*2)*64 + l)*8]);       \
        const short8 bsv1 = *(const short8*)(&B[((9 + i*2)*64 + l)*8]);       \
        _Pragma("unroll")                                                     \
        for (int mt = 0; mt < 2; ++mt) {                                      \
          if (actc[mt]) {                                                     \
            acc[mt][2 + 2*i] = __builtin_amdgcn_mfma_f32_16x16x32_bf16(       \
                a[0][mt], bsv0, acc[mt][2 + 2*i], 0, 0, 0);                   \
            acc[mt][3 + 2*i] = __builtin_amdgcn_mfma_f32_16x16x32_bf16(       \
                a[0][mt], bsv1, acc[mt][3 + 2*i], 0, 0, 0);                   \
          }                                                                   \
        }                                                                     \
      }                                                                       \
      __builtin_amdgcn_s_setprio(0);                                          \
    }                                                                         \
    if (DOREF) {  /* a[0] dead after Ksv: refill now (prio 0) */              \
      _Pragma("unroll")                                                       \
      for (int mt = 0; mt < 2; ++mt) {                                        \
        short8 v = (short8)(short)0;                                          \
        if (vln[mt]) v = *(const short8*)(xb + uoffn[mt]);                    \
        a[0][mt] = v;                                                         \
      }                                                                       \
    }                                                                         \
    {                                                                         \
      const short8 bv0 = anyact ? *(const short8*)(&B[(14*64 + l)*8])         \
                                : (short8)(short)0;                           \
      const short8 bv1 = anyact ? *(const short8*)(&B[(15*64 + l)*8])         \
                                : (short8)(short)0;                           \
      _Pragma("unroll")                                                       \
      for (int i = 0; i < 3; ++i) {                                           \
        if (anyact) {                                                         \
          __builtin_amdgcn_s_setprio(1);                                      \
          _Pragma("unroll")                                                   \
          for (int mt = 0; mt < 2; ++mt) {                                    \
            if (actc[mt]) {                                                   \
              acc[mt][2 + 2*i] = __builtin_amdgcn_mfma_f32_16x16x32_bf16(     \
                  a[1 + i][mt], bv0, acc[mt][2 + 2*i], 0, 0, 0);              \
              acc[mt][3 + 2*i] = __builtin_amdgcn_mfma_f32_16x16x32_bf16(     \
                  a[1 + i][mt], bv1, acc[mt][3 + 2*i], 0, 0, 0);              \
            }                                                                 \
          }                                                                   \
          __builtin_amdgcn_s_setprio(0);                                      \
        }                                                                     \
        if (DOREF) {  /* a[1+i] dead after vv_i: refill now (prio 0) */       \
          _Pragma("unroll")                                                   \
          for (int mt = 0; mt < 2; ++mt) {                                    \
            short8 v = (short8)(short)0;                                      \
            if (vln[mt]) v = *(const short8*)(xb + uoffn[mt] + (1 + i)*64);   \
            a[1 + i][mt] = v;                                                 \
          }                                                                   \
        }                                                                     \
      }                                                                       \
    }                                                                         \
    if (DOREF) {                                                              \
      _Pragma("unroll")                                                       \
      for (int mt = 0; mt < 2; ++mt) actc[mt] = actn[mt];                     \
    }                                                                         \
  }

  for (int j = 0; j < 62; ++j) {
    const int cur = j & 1;
    const int sb  = (cur ^ 1) * 16384;      // stage slot (ush index)
    const bool h3 = (j < 61);

    // stage tiles 2j+2 (and 2j+3) into the other slot
    {
      const unsigned short* s0 = g_kern + (size_t)(2*j + 2) * KTILE;
      GLD16(s0 + wv*512 + l*8,        &Buf[sb + wv*512]);
      GLD16(s0 + 4096 + wv*512 + l*8, &Buf[sb + 4096 + wv*512]);
      if (h3) {
        const unsigned short* s1 = g_kern + (size_t)(2*j + 3) * KTILE;
        GLD16(s1 + wv*512 + l*8,        &Buf[sb + 8192 + wv*512]);
        GLD16(s1 + 4096 + wv*512 + l*8, &Buf[sb + 12288 + wv*512]);
      }
    }
    // prefetch indices 2j+2, 2j+3
    {
      const int* ip2 = nidx + (size_t)(2*j + 2) * NPTS + m0;
      #pragma unroll
      for (int mt = 0; mt < 2; ++mt)
        iK2[mt] = __builtin_nontemporal_load(ip2 + mt*16 + lr);
      if (h3) {
        const int* ip3 = nidx + (size_t)(2*j + 3) * NPTS + m0;
        #pragma unroll
        for (int mt = 0; mt < 2; ++mt)
          iK3[mt] = __builtin_nontemporal_load(ip3 + mt*16 + lr);
      }
    }

    KO_SECTION(cur * 16384,        iK1, true)   // k0 = 2j, refill -> k1
    KO_SECTION(cur * 16384 + 8192, iK2, true)   // k1 = 2j+1, refill -> 2j+2

    #pragma unroll
    for (int mt = 0; mt < 2; ++mt) iK1[mt] = iK3[mt];
    __syncthreads();
  }

  // tail: ko = 124 (tile staged at j=61 into slot 0; a[]/actc ready)
  KO_SECTION(0, iK1, false)
  __syncthreads();

#undef KO_SECTION

  // epilogue: planar acc -> ORIGINAL interleaved columns.
  // q<2: oc = q*16+lr. q>=2: i=(q-2)>>1, h=(q-2)&1 -> oc = 32+(h*16+lr)*3+i.
  if (of32) {
    float* of = (float*)out;
    #pragma unroll
    for (int mt = 0; mt < 2; ++mt)
      #pragma unroll
      for (int q = 0; q < 8; ++q) {
        const int oc = (q < 2) ? (q*16 + lr)
                               : 32 + (((q - 2) & 1)*16 + lr)*3 + ((q - 2) >> 1);
        #pragma unroll
        for (int r = 0; r < 4; ++r)
          __builtin_nontemporal_store(
              acc[mt][q][r],
              &of[(size_t)(m0 + mt*16 + lk*4 + r) * 128 + oc]);
      }
  } else {
    // block-wide LDS bounce (XOR-swizzled, un-permutes), coalesced nt stores
    unsigned short* eb = &Buf[0];   // 64 KB = 256 rows x 128 cols
    #pragma unroll
    for (int mt = 0; mt < 2; ++mt)
      #pragma unroll
      for (int q = 0; q < 8; ++q) {
        const int oc = (q < 2) ? (q*16 + lr)
                               : 32 + (((q - 2) & 1)*16 + lr)*3 + ((q - 2) >> 1);
        #pragma unroll
        for (int r = 0; r < 4; ++r) {
          const int row = wv*32 + mt*16 + lk*4 + r;    // 0..255 local
          eb[row*128 + (oc ^ ((row & 7) << 3))] = f2bf(acc[mt][q][r]);
        }
      }
    __syncthreads();
    unsigned short* ob = (unsigned short*)out;
    const int row = tid >> 1;
    #pragma unroll
    for (int it = 0; it < 8; ++it) {
      const int ub = (tid & 1)*64 + it*8;
      const short8 v = *(const short8*)(&eb[row*128 + (ub ^ ((row & 7) << 3))]);
      __builtin_nontemporal_store(
          v, (short8*)&ob[(size_t)(blockIdx.x*256 + row) * 128 + ub]);
    }
  }
}

extern "C" void kernel_launch(void* const* d_in, const int* in_sizes, int n_in,
                              void* d_out, int out_size, void* d_ws, size_t ws_size,
                              hipStream_t stream) {
  const void* weight = d_in[1];
  const void* wscs   = d_in[2];
  const void* wscv   = d_in[3];
  const int*  nidx   = (const int*)d_in[4];

  hipLaunchKernelGGL(k_detect, dim3(1), dim3(64), 0, stream,
                     (const unsigned short*)d_in[0], (const unsigned short*)d_in[1],
                     (const unsigned short*)d_in[2], (const unsigned short*)d_in[3]);
  hipLaunchKernelGGL(k_convx, dim3(NPTS * 128 / (256 * 8)), dim3(256), 0, stream, d_in[0]);
  hipLaunchKernelGGL(gen_kern, dim3(NOFF), dim3(256), 0, stream, weight, wscs, wscv);
  hipLaunchKernelGGL(conv_main, dim3(NPTS / 256), dim3(512), 0, stream,
                     nidx, d_out);
}